// Round 3
// baseline (136.543 us; speedup 1.0000x reference)
//
#include <hip/hip_runtime.h>

// Problem constants (fixed by the reference file).
#define DIN  4096
#define NG   4096          // NUM_GATES = DOUT/3
#define BS   4096
#define ROWS_PER_BLOCK 8
#define GPT  4             // gates per thread
#define BT   256           // block threads
// Block covers BT*GPT = 1024 gates -> x-window floats [12*TG0, 12*TG0+3073).
// Stage 3076 floats = 769 float4s (wrap handled per-float4; never splits one).
#define WIN4 769
#define WINF 3080          // LDS floats (3076 + pad)

typedef float v4f __attribute__((ext_vector_type(4)));

// out[b,g] = w0*x[b,(3g+1)&4095] + w1*x[b,(3g+2)&4095] + w2*x[b,(3g+3)&4095] + w3
// (w0..w3) = softmax(wgts[g,0,0..3]). Reference's signals[:, :, ::3] selects only
// row 0 of M = [1,0,0,0,0] -> out = s[...,0]; v4/v5 and rows 1..2 are dead code.
//
// R3: stage x-window in LDS via coalesced float4 loads (R2 was L1-bound on
// 48B-lane-stride dwordx4: 3072B span per wave instr, ~3x TA work -> 48us).
// LDS compute reads: lane i ds_read_b128 at float offset 12i -> every 8 lanes
// cover all 32 banks exactly once -> conflict-free.
__global__ __launch_bounds__(BT) void fredkin_s0_lds(
    const float* __restrict__ x,
    const float* __restrict__ wgts,
    float* __restrict__ out)
{
    __shared__ float xs[WINF];

    const int tid = threadIdx.x;
    const int tg  = blockIdx.x * BT + tid;   // gate-group id (0..1023)
    const int g0  = tg * GPT;

    // Softmax of wgts[g,0,:] for this thread's 4 gates (row-0 at float offset 12g, 16B aligned).
    float4 w[GPT];
#pragma unroll
    for (int j = 0; j < GPT; ++j) {
        float4 r = *reinterpret_cast<const float4*>(wgts + (size_t)(g0 + j) * 12);
        float m  = fmaxf(fmaxf(r.x, r.y), fmaxf(r.z, r.w));
        float e0 = __expf(r.x - m);
        float e1 = __expf(r.y - m);
        float e2 = __expf(r.z - m);
        float e3 = __expf(r.w - m);
        float inv = 1.0f / (e0 + e1 + e2 + e3);
        w[j] = make_float4(e0 * inv, e1 * inv, e2 * inv, e3 * inv);
    }

    const int base = blockIdx.x * (BT * 12);          // block window base (float idx, mult of 4)
    const int lb   = 12 * tid;                        // this thread's LDS float offset

    const int brow = blockIdx.y * ROWS_PER_BLOCK;
    const float* xr   = x   + (size_t)brow * DIN;
    float*       orow = out + (size_t)brow * NG + g0;

    for (int r = 0; r < ROWS_PER_BLOCK; ++r) {
        // Coalesced staging: unit-stride float4 across lanes; &4095 wrap is
        // float4-granular (base and 4*i are multiples of 4).
#pragma unroll
        for (int i = tid; i < WIN4; i += BT) {
            const int gi = (base + 4 * i) & (DIN - 1);
            *reinterpret_cast<float4*>(&xs[4 * i]) =
                *reinterpret_cast<const float4*>(xr + gi);
        }
        __syncthreads();

        float4 f0 = *reinterpret_cast<const float4*>(&xs[lb]);      // e0..e3
        float4 f1 = *reinterpret_cast<const float4*>(&xs[lb + 4]);  // e4..e7
        float4 f2 = *reinterpret_cast<const float4*>(&xs[lb + 8]);  // e8..e11
        float  e12 = xs[lb + 12];

        v4f o;
        o.x = fmaf(w[0].x, f0.y, fmaf(w[0].y, f0.z, fmaf(w[0].z, f0.w, w[0].w)));
        o.y = fmaf(w[1].x, f1.x, fmaf(w[1].y, f1.y, fmaf(w[1].z, f1.z, w[1].w)));
        o.z = fmaf(w[2].x, f1.w, fmaf(w[2].y, f2.x, fmaf(w[2].z, f2.y, w[2].w)));
        o.w = fmaf(w[3].x, f2.z, fmaf(w[3].y, f2.w, fmaf(w[3].z, e12, w[3].w)));

        __builtin_nontemporal_store(o, reinterpret_cast<v4f*>(orow));

        __syncthreads();   // xs reused next row
        xr   += DIN;
        orow += NG;
    }
}

extern "C" void kernel_launch(void* const* d_in, const int* in_sizes, int n_in,
                              void* d_out, int out_size, void* d_ws, size_t ws_size,
                              hipStream_t stream) {
    const float* x    = (const float*)d_in[0];   // (BS, DIN) fp32
    const float* wgts = (const float*)d_in[1];   // (NG, 3, 4) fp32
    // d_in[2] (connections) is deterministic: (3g+1+j) % DIN — computed inline.
    float* out = (float*)d_out;                  // (BS, NG) fp32

    dim3 grid(NG / (BT * GPT),        // 4
              BS / ROWS_PER_BLOCK);   // 512  -> 2048 blocks = 8 blocks/CU
    fredkin_s0_lds<<<grid, dim3(BT), 0, stream>>>(x, wgts, out);
}

// Round 4
// 124.387 us; speedup vs baseline: 1.0977x; 1.0977x over previous
//
#include <hip/hip_runtime.h>

// Problem constants (fixed by the reference file).
#define DIN  4096
#define NG   4096          // NUM_GATES = DOUT/3
#define BS   4096
#define RPB  8             // rows per block -> 512 blocks = 2 blocks/CU, 32 waves/CU
#define BT   1024          // 16 waves; block covers ALL 4096 gates (4 per thread)
#define WROW 4112          // 4096 floats + 16 pad (wrap tail, keeps 16B alignment)

typedef float v4f __attribute__((ext_vector_type(4)));

// out[b,g] = w0*x[b,(3g+1)&4095] + w1*x[b,(3g+2)&4095] + w2*x[b,(3g+3)&4095] + w3
// (w0..w3) = softmax(wgts[g,0,0..3]). Reference's signals[:, :, ::3] selects only
// row 0 of M = [1,0,0,0,0] -> out = s[...,0]; v4/v5 and rows 1..2 are dead code.
//
// R4: full-row LDS staging (each row fetched exactly once -> FETCH ~64MB),
// one coalesced float4 per thread, double-buffered with ONE barrier per row;
// next row's global load issued before the barrier. ds_read_b128 at 48B lane
// stride = 2-way bank aliasing per 16-lane phase -> free (m136).
__global__ __launch_bounds__(BT) void fredkin_s0_dbuf(
    const float* __restrict__ x,
    const float* __restrict__ wgts,
    float* __restrict__ out)
{
    __shared__ float xs[2][WROW];

    const int tid = threadIdx.x;
    const int g0  = 4 * tid;

    // Softmax of wgts[g,0,:] for this thread's 4 gates (row-0 at float offset 12g,
    // 16B aligned). Strided, but once per block, amortized over RPB rows; wgts is
    // 192KB -> L2-resident.
    float4 w[4];
#pragma unroll
    for (int j = 0; j < 4; ++j) {
        float4 r = *reinterpret_cast<const float4*>(wgts + (size_t)(g0 + j) * 12);
        float m  = fmaxf(fmaxf(r.x, r.y), fmaxf(r.z, r.w));
        float e0 = __expf(r.x - m);
        float e1 = __expf(r.y - m);
        float e2 = __expf(r.z - m);
        float e3 = __expf(r.w - m);
        float inv = 1.0f / (e0 + e1 + e2 + e3);
        w[j] = make_float4(e0 * inv, e1 * inv, e2 * inv, e3 * inv);
    }

    const int lb = (12 * tid) & (DIN - 1);   // window start in LDS (reads lb+1..lb+12)

    const int brow = blockIdx.x * RPB;
    const float* xr   = x   + (size_t)brow * DIN + 4 * tid;   // this thread's float4
    float*       orow = out + (size_t)brow * NG + g0;

    float4 v = *reinterpret_cast<const float4*>(xr);          // prefetch row 0

    for (int r = 0; r < RPB; ++r) {
        float* buf = xs[r & 1];
        *reinterpret_cast<float4*>(&buf[4 * tid]) = v;
        if (tid < 4)                                          // pad: replicate floats 0..15
            *reinterpret_cast<float4*>(&buf[DIN + 4 * tid]) = v;

        if (r + 1 < RPB)                                      // prefetch next row (in flight
            v = *reinterpret_cast<const float4*>(xr + DIN);   // until drained at barrier)

        __syncthreads();   // only barrier: staging(r) done before compute(r);
                           // compute(r-1) used the OTHER buffer -> no trailing barrier

        float4 f0 = *reinterpret_cast<const float4*>(&buf[lb]);      // e0..e3
        float4 f1 = *reinterpret_cast<const float4*>(&buf[lb + 4]);  // e4..e7
        float4 f2 = *reinterpret_cast<const float4*>(&buf[lb + 8]);  // e8..e11
        float  e12 = buf[lb + 12];                                   // pad-covered wrap

        v4f o;
        o.x = fmaf(w[0].x, f0.y, fmaf(w[0].y, f0.z, fmaf(w[0].z, f0.w, w[0].w)));
        o.y = fmaf(w[1].x, f1.x, fmaf(w[1].y, f1.y, fmaf(w[1].z, f1.z, w[1].w)));
        o.z = fmaf(w[2].x, f1.w, fmaf(w[2].y, f2.x, fmaf(w[2].z, f2.y, w[2].w)));
        o.w = fmaf(w[3].x, f2.z, fmaf(w[3].y, f2.w, fmaf(w[3].z, e12, w[3].w)));

        __builtin_nontemporal_store(o, reinterpret_cast<v4f*>(orow));

        xr   += DIN;
        orow += NG;
    }
}

extern "C" void kernel_launch(void* const* d_in, const int* in_sizes, int n_in,
                              void* d_out, int out_size, void* d_ws, size_t ws_size,
                              hipStream_t stream) {
    const float* x    = (const float*)d_in[0];   // (BS, DIN) fp32
    const float* wgts = (const float*)d_in[1];   // (NG, 3, 4) fp32
    // d_in[2] (connections) is deterministic: (3g+1+j) % DIN — computed inline.
    float* out = (float*)d_out;                  // (BS, NG) fp32

    fredkin_s0_dbuf<<<dim3(BS / RPB), dim3(BT), 0, stream>>>(x, wgts, out);
}